// Round 1
// baseline (293.665 us; speedup 1.0000x reference)
//
#include <hip/hip_runtime.h>

#define GRID 2048
#define BLK  256
#define NWAVES (BLK / 64)
#define STRIDE (GRID * BLK)

// First 100 MB of fr (6.25M float4) is loaded CACHED so it stays L3-resident
// alongside nb+mn. Resident set = 80 + 40 + 100 = 220 MB < 256 MiB L3.
#define F_CACHE_F4 6250000

// Native clang vector type — __builtin_nontemporal_load requires this,
// not HIP_vector_type<float,4>.
typedef float floatx4 __attribute__((ext_vector_type(4)));

// d * rcp(den) with v_rcp_f32 (<=1 ulp) — threshold slack is enormous.
__device__ __forceinline__ float frcp(float x) {
    return __builtin_amdgcn_rcpf(x);
}

// Partial sums. L3 strategy: nb+mn (120 MB) + head of fr (100 MB) fit in the
// 256 MiB Infinity Cache and are loaded normally (stay resident across
// iterations -> L3 hits); only the fr tail (60 MB) is loaded non-temporally
// (evict-first, clean HBM stream). Block-parity loop order overlaps the
// L3-hit phase with the HBM phase.
__global__ __launch_bounds__(BLK) void pacmap_partial_kernel(
    const floatx4* __restrict__ nb, int n_n,
    const floatx4* __restrict__ mn, int n_m,
    const floatx4* __restrict__ fr, int n_f,
    float* __restrict__ ws) {

    const int tid = blockIdx.x * BLK + threadIdx.x;

    float s_n = 0.0f, s_m = 0.0f, s_f = 0.0f;

    auto do_near = [&]() {
        for (int i = tid; i < n_n; i += STRIDE) {
            floatx4 p = nb[i];
            float dx = p.x - p.z, dy = p.y - p.w;
            float d  = fmaf(dx, dx, fmaf(dy, dy, 1.0f));
            s_n += d * frcp(10.0f + d);
        }
    };
    auto do_mid = [&]() {
        for (int i = tid; i < n_m; i += STRIDE) {
            floatx4 p = mn[i];
            float dx = p.x - p.z, dy = p.y - p.w;
            float d  = fmaf(dx, dx, fmaf(dy, dy, 1.0f));
            s_m += d * frcp(10000.0f + d);
        }
    };
    auto do_far = [&]() {
        const int nc = (n_f < F_CACHE_F4) ? n_f : F_CACHE_F4;
        int i = tid;
        // Head: cached loads -> L3-resident across iterations.
        for (; i < nc; i += STRIDE) {
            floatx4 p = fr[i];
            float dx = p.x - p.z, dy = p.y - p.w;
            float d  = fmaf(dx, dx, fmaf(dy, dy, 1.0f));
            s_f += frcp(1.0f + d);
        }
        // Tail: non-temporal, clean HBM stream (don't evict the resident set).
        for (; i < n_f; i += STRIDE) {
            floatx4 p = __builtin_nontemporal_load(&fr[i]);
            float dx = p.x - p.z, dy = p.y - p.w;
            float d  = fmaf(dx, dx, fmaf(dy, dy, 1.0f));
            s_f += frcp(1.0f + d);
        }
    };

    if (blockIdx.x & 1) {
        do_far();
        do_near();
        do_mid();
    } else {
        do_near();
        do_mid();
        do_far();
    }

    // wave-64 shuffle reduction
    #pragma unroll
    for (int off = 32; off > 0; off >>= 1) {
        s_n += __shfl_down(s_n, off, 64);
        s_m += __shfl_down(s_m, off, 64);
        s_f += __shfl_down(s_f, off, 64);
    }

    __shared__ float sm[3][NWAVES];
    const int lane = threadIdx.x & 63;
    const int wid  = threadIdx.x >> 6;
    if (lane == 0) {
        sm[0][wid] = s_n;
        sm[1][wid] = s_m;
        sm[2][wid] = s_f;
    }
    __syncthreads();
    if (threadIdx.x == 0) {
        float a = 0.0f, b = 0.0f, c = 0.0f;
        #pragma unroll
        for (int i = 0; i < NWAVES; ++i) {
            a += sm[0][i];
            b += sm[1][i];
            c += sm[2][i];
        }
        ws[blockIdx.x]            = a;
        ws[GRID + blockIdx.x]     = b;
        ws[2 * GRID + blockIdx.x] = c;
    }
}

// Single-block finalize: reduce GRID partials per loss, apply phase weights.
__global__ __launch_bounds__(BLK) void pacmap_finalize_kernel(
    const float* __restrict__ ws,
    const int* __restrict__ iter_p,
    float* __restrict__ out) {

    float s_n = 0.0f, s_m = 0.0f, s_f = 0.0f;
    for (int i = threadIdx.x; i < GRID; i += BLK) {
        s_n += ws[i];
        s_m += ws[GRID + i];
        s_f += ws[2 * GRID + i];
    }

    #pragma unroll
    for (int off = 32; off > 0; off >>= 1) {
        s_n += __shfl_down(s_n, off, 64);
        s_m += __shfl_down(s_m, off, 64);
        s_f += __shfl_down(s_f, off, 64);
    }

    __shared__ float sm[3][NWAVES];
    const int lane = threadIdx.x & 63;
    const int wid  = threadIdx.x >> 6;
    if (lane == 0) {
        sm[0][wid] = s_n;
        sm[1][wid] = s_m;
        sm[2][wid] = s_f;
    }
    __syncthreads();
    if (threadIdx.x == 0) {
        float a = 0.0f, b = 0.0f, c = 0.0f;
        #pragma unroll
        for (int i = 0; i < NWAVES; ++i) {
            a += sm[0][i];
            b += sm[1][i];
            c += sm[2][i];
        }

        const int it = *iter_p;
        float w_n, w_m, w_f;
        if (it < 101) {
            const float frac = (0.0f - 1.0f) / (101.0f - 1.0f);
            w_n = 2.0f;
            w_m = 1000.0f * (1.0f - frac) + 3.0f * frac;
            w_f = 1.0f;
        } else if (it < 201) {
            w_n = 3.0f; w_m = 3.0f; w_f = 1.0f;
        } else {
            w_n = 1.0f; w_m = 0.0f; w_f = 1.0f;
        }
        out[0] = a * w_n + b * w_m + c * w_f;
    }
}

extern "C" void kernel_launch(void* const* d_in, const int* in_sizes, int n_in,
                              void* d_out, int out_size, void* d_ws, size_t ws_size,
                              hipStream_t stream) {
    const floatx4* nb = (const floatx4*)d_in[0];
    const floatx4* mn = (const floatx4*)d_in[1];
    const floatx4* fr = (const floatx4*)d_in[2];
    const int* iter_p = (const int*)d_in[3];

    const int n_n = in_sizes[0] / 4;
    const int n_m = in_sizes[1] / 4;
    const int n_f = in_sizes[2] / 4;

    float* ws  = (float*)d_ws;
    float* out = (float*)d_out;

    pacmap_partial_kernel<<<GRID, BLK, 0, stream>>>(nb, n_n, mn, n_m, fr, n_f, ws);
    pacmap_finalize_kernel<<<1, BLK, 0, stream>>>(ws, iter_p, out);
}